// Round 2
// baseline (909.754 us; speedup 1.0000x reference)
//
#include <hip/hip_runtime.h>
#include <hip/hip_bf16.h>

#define N_NODES 100000
#define N_EDGES 1600000
#define IN_DIM  500
#define HID     128
#define KDIM    512   // HID * (DEG+1)
#define NB      782   // ceil(N_NODES/128) buckets
#define BCAP    4096  // bucket capacity (expected 2046, >20 sigma headroom)

typedef __attribute__((ext_vector_type(8))) short bf16x8;
typedef __attribute__((ext_vector_type(4))) float f32x4;

__device__ inline short f2bf(float x) {
    union { float f; unsigned u; } v; v.f = x;
    unsigned r = (v.u + 0x7FFFu + ((v.u >> 16) & 1u)) >> 16;  // RNE
    return (short)r;
}
__device__ inline float bf_lo(unsigned u) { union { unsigned u; float f; } v; v.u = u << 16; return v.f; }
__device__ inline float bf_hi(unsigned u) { union { unsigned u; float f; } v; v.u = u & 0xFFFF0000u; return v.f; }
__device__ inline float bf2f(unsigned short s) { union { unsigned u; float f; } v; v.u = ((unsigned)s) << 16; return v.f; }

// ---------------------------------------------------------------------------
// CSR build, two-pass binned (unchanged)
// ---------------------------------------------------------------------------

__global__ __launch_bounds__(256) void bin_kernel(const int* __restrict__ ei,
                                                  int* __restrict__ bcnt,
                                                  unsigned* __restrict__ buf) {
    int e = blockIdx.x * 256 + threadIdx.x;
    if (e < N_EDGES) {
        int r = ei[e];
        int c = ei[N_EDGES + e];
        int b = r >> 7;
        int p = atomicAdd(&bcnt[b * 16], 1);   // stride 64 B: spread L2 slices
        if (p < BCAP) buf[b * BCAP + p] = ((unsigned)(r & 127) << 17) | (unsigned)c;
    }
}

__global__ __launch_bounds__(1024) void bscan_kernel(const int* __restrict__ bcnt,
                                                     int* __restrict__ bbase) {
    __shared__ int buf[1024];
    const int tid = threadIdx.x;
    int v = (tid < NB) ? bcnt[tid * 16] : 0;
    buf[tid] = v;
    __syncthreads();
    for (int off = 1; off < 1024; off <<= 1) {
        int t = (tid >= off) ? buf[tid - off] : 0;
        __syncthreads();
        buf[tid] += t;
        __syncthreads();
    }
    if (tid < NB) bbase[tid] = buf[tid] - v;   // exclusive
}

__global__ __launch_bounds__(256) void place_kernel(const unsigned* __restrict__ buf,
                                                    const int* __restrict__ bcnt,
                                                    const int* __restrict__ bbase,
                                                    int* __restrict__ row_start,
                                                    int* __restrict__ col_sorted) {
    __shared__ int hist[128];
    __shared__ int scan[128];
    __shared__ int cur[128];
    const int b = blockIdx.x, tid = threadIdx.x;
    int cnt = bcnt[b * 16]; if (cnt > BCAP) cnt = BCAP;
    const int base = bbase[b];
    if (tid < 128) hist[tid] = 0;
    __syncthreads();
    for (int i = tid; i < cnt; i += 256)
        atomicAdd(&hist[buf[b * BCAP + i] >> 17], 1);
    __syncthreads();
    if (tid < 128) scan[tid] = hist[tid];
    __syncthreads();
    for (int off = 1; off < 128; off <<= 1) {
        int t = (tid < 128 && tid >= off) ? scan[tid - off] : 0;
        __syncthreads();
        if (tid < 128) scan[tid] += t;
        __syncthreads();
    }
    if (tid < 128) {
        int excl = scan[tid] - hist[tid] + base;
        cur[tid] = excl;
        int r = b * 128 + tid;
        if (r < N_NODES) row_start[r] = excl;
        if (r == N_NODES - 1) row_start[N_NODES] = excl + hist[tid];
    }
    __syncthreads();
    for (int i = tid; i < cnt; i += 256) {
        unsigned u = buf[b * BCAP + i];
        int rl = (int)(u >> 17);
        int c  = (int)(u & 0x1FFFFu);
        int pos = atomicAdd(&cur[rl], 1);
        col_sorted[pos] = c;
    }
}

// ---------------------------------------------------------------------------
// Repacks (once per launch)
// ---------------------------------------------------------------------------
__global__ __launch_bounds__(256) void repack_cheb(const float* __restrict__ cheb,
                                                   unsigned short* __restrict__ Bmat) {
    int idx = blockIdx.x * 256 + threadIdx.x;   // < 128*512
    int o = idx >> 9;
    int k = idx & 511;
    int i = k >> 2;
    int d = k & 3;
    Bmat[idx] = (unsigned short)f2bf(cheb[i * 512 + o * 4 + d]);
}
__global__ __launch_bounds__(256) void repack_w(const float* __restrict__ W,
                                                unsigned short* __restrict__ Wmat) {
    int idx = blockIdx.x * 256 + threadIdx.x;   // < 128*512
    int o = idx >> 9;
    int k = idx & 511;
    Wmat[idx] = (k < IN_DIM) ? (unsigned short)f2bf(W[k * HID + o]) : 0;
}
__global__ __launch_bounds__(256) void repack_c2w(const float* __restrict__ cheb,
                                                  const float* __restrict__ Wout,
                                                  unsigned short* __restrict__ C2W) {
    int idx = blockIdx.x * 256 + threadIdx.x;   // < 16*512
    if (idx >= 16 * 512) return;
    int o16 = idx >> 9;
    int k   = idx & 511;
    const float* cb = cheb + 65536 + (k >> 2) * 512 + (k & 3);
    float s = 0.f;
#pragma unroll 4
    for (int o = 0; o < 128; o++) s += cb[o * 4] * Wout[o * 16 + o16];
    C2W[o16 * 512 + k] = (unsigned short)f2bf(s);
}

// ---------------------------------------------------------------------------
// MFMA GEMM 1: h = x @ W_in  [100000 x 500(512)] @ [500 x 128] -> bf16
// 64x128 tile, BK=32, dbuf LDS + register prefetch.
// Output written SLICE-MAJOR: out_sm[slice=nt][node][16] (same store count,
// different addresses) so the following spmm can gather per-XCD L2-resident
// 3.2 MB slices.
// ---------------------------------------------------------------------------
__global__ __launch_bounds__(256, 4) void gemm_xw(const float* __restrict__ x,
                                                  const unsigned short* __restrict__ Wmat,
                                                  unsigned short* __restrict__ out) {
    __shared__ __align__(16) short As[2][64][40];    // 10.25 KB
    __shared__ __align__(16) short Bs[2][128][40];   // 20.5  KB
    const int tid  = threadIdx.x;
    const int lane = tid & 63;
    const int wave = tid >> 6;
    const int quad = lane >> 4;
    const int l16  = lane & 15;
    const int n0   = blockIdx.x * 64;
    const int ar   = tid >> 2;     // A row 0..63
    const int ah   = tid & 3;      // 8-float segment
    const int br   = tid >> 1;     // B row 0..127
    const int bh   = tid & 1;      // 16-short segment

    int nA = n0 + ar; if (nA >= N_NODES) nA = N_NODES - 1;
    const float* __restrict__ xrow = x + (long)nA * IN_DIM;

    f32x4 acc[8];
#pragma unroll
    for (int nt = 0; nt < 8; nt++)
#pragma unroll
        for (int r = 0; r < 4; r++) acc[nt][r] = 0.f;

    auto loadA = [&](int kt, float (&v)[8]) {
        const int kb = kt * 32 + ah * 8;
        if (kb + 8 <= IN_DIM) {
            const float4* s4 = (const float4*)(xrow + kb);
            float4 a0 = s4[0], a1 = s4[1];
            v[0]=a0.x; v[1]=a0.y; v[2]=a0.z; v[3]=a0.w;
            v[4]=a1.x; v[5]=a1.y; v[6]=a1.z; v[7]=a1.w;
        } else {
#pragma unroll
            for (int q = 0; q < 8; q++) v[q] = (kb + q < IN_DIM) ? xrow[kb + q] : 0.f;
        }
    };
    auto loadB = [&](int kt, bf16x8 (&w)[2]) {
        w[0] = *(const bf16x8*)&Wmat[br * 512 + kt * 32 + bh * 16];
        w[1] = *(const bf16x8*)&Wmat[br * 512 + kt * 32 + bh * 16 + 8];
    };
    auto storeA = [&](int buf, const float (&v)[8]) {
        short t[8];
#pragma unroll
        for (int q = 0; q < 8; q++) t[q] = f2bf(v[q]);
        *(bf16x8*)&As[buf][ar][ah * 8] = *(bf16x8*)&t[0];
    };
    auto storeB = [&](int buf, const bf16x8 (&w)[2]) {
        *(bf16x8*)&Bs[buf][br][bh * 16]     = w[0];
        *(bf16x8*)&Bs[buf][br][bh * 16 + 8] = w[1];
    };
    auto mfmaTile = [&](int buf) {
        bf16x8 a = *(const bf16x8*)&As[buf][wave * 16 + l16][quad * 8];
#pragma unroll
        for (int nt = 0; nt < 8; nt++) {
            bf16x8 b = *(const bf16x8*)&Bs[buf][nt * 16 + l16][quad * 8];
            acc[nt] = __builtin_amdgcn_mfma_f32_16x16x32_bf16(a, b, acc[nt], 0, 0, 0);
        }
    };

    float  va[8], vb[8];
    bf16x8 wa[2], wb[2];
    loadA(0, va); loadB(0, wa);
    for (int kt = 0; kt < 16; kt += 2) {
        storeA(0, va); storeB(0, wa);
        loadA(kt + 1, vb); loadB(kt + 1, wb);
        __syncthreads();
        mfmaTile(0);
        storeA(1, vb); storeB(1, wb);
        if (kt + 2 < 16) { loadA(kt + 2, va); loadB(kt + 2, wa); }
        __syncthreads();
        mfmaTile(1);
    }

    {
        int mrow = n0 + wave * 16 + quad * 4;
#pragma unroll
        for (int r = 0; r < 4; r++) {
            int n = mrow + r;
            if (n < N_NODES) {
#pragma unroll
                for (int nt = 0; nt < 8; nt++)
                    out[((long)nt * N_NODES + n) * 16 + l16] = (unsigned short)f2bf(acc[nt][r]);
            }
        }
    }
}

// ---------------------------------------------------------------------------
// MFMA GEMM 2 (layer 0): out = Basis(h) @ C1  [N x 512]@[512 x 128]
// Reads h ROW-major (spmm output); writes SLICE-MAJOR for the next spmm.
// ---------------------------------------------------------------------------
__global__ __launch_bounds__(256, 4) void cheb_gemm(const unsigned short* __restrict__ h,
                                                    const unsigned short* __restrict__ Bmat,
                                                    unsigned short* __restrict__ out) {
    __shared__ __align__(16) short As[2][64][40];
    __shared__ __align__(16) short Bs[2][128][40];
    const int tid  = threadIdx.x;
    const int lane = tid & 63;
    const int wave = tid >> 6;
    const int quad = lane >> 4;
    const int l16  = lane & 15;
    const int n0   = blockIdx.x * 64;
    const int ar   = tid >> 2;
    const int sub  = tid & 3;      // 2 h-features each
    const int br   = tid >> 1;
    const int bh   = tid & 1;

    int nA = n0 + ar; if (nA >= N_NODES) nA = N_NODES - 1;
    const unsigned short* __restrict__ hrow = h + (long)nA * HID;

    f32x4 acc[8];
#pragma unroll
    for (int nt = 0; nt < 8; nt++)
#pragma unroll
        for (int r = 0; r < 4; r++) acc[nt][r] = 0.f;

    auto loadA = [&](int kt, unsigned& v) {
        v = *(const unsigned*)(hrow + kt * 8 + sub * 2);   // 2 bf16 features
    };
    auto loadB = [&](int kt, bf16x8 (&w)[2]) {
        w[0] = *(const bf16x8*)&Bmat[br * 512 + kt * 32 + bh * 16];
        w[1] = *(const bf16x8*)&Bmat[br * 512 + kt * 32 + bh * 16 + 8];
    };
    auto storeA = [&](int buf, unsigned v) {
        float hx[2] = {bf_lo(v), bf_hi(v)};
        short t[8];
#pragma unroll
        for (int q = 0; q < 2; q++) {
            float xx = fminf(fmaxf(hx[q], -15.f), 15.f);
            float e  = __expf(2.f * xx);
            float tt = (e - 1.f) / (e + 1.f);     // tanh
            float T2 = 2.f * tt * tt - 1.f;
            float T3 = 2.f * tt * T2 - tt;
            t[q * 4 + 0] = (short)0x3F80;         // bf16(1.0)
            t[q * 4 + 1] = f2bf(tt);
            t[q * 4 + 2] = f2bf(T2);
            t[q * 4 + 3] = f2bf(T3);
        }
        *(bf16x8*)&As[buf][ar][sub * 8] = *(bf16x8*)&t[0];
    };
    auto storeB = [&](int buf, const bf16x8 (&w)[2]) {
        *(bf16x8*)&Bs[buf][br][bh * 16]     = w[0];
        *(bf16x8*)&Bs[buf][br][bh * 16 + 8] = w[1];
    };
    auto mfmaTile = [&](int buf) {
        bf16x8 a = *(const bf16x8*)&As[buf][wave * 16 + l16][quad * 8];
#pragma unroll
        for (int nt = 0; nt < 8; nt++) {
            bf16x8 b = *(const bf16x8*)&Bs[buf][nt * 16 + l16][quad * 8];
            acc[nt] = __builtin_amdgcn_mfma_f32_16x16x32_bf16(a, b, acc[nt], 0, 0, 0);
        }
    };

    unsigned va, vb;
    bf16x8   wa[2], wb[2];
    loadA(0, va); loadB(0, wa);
    for (int kt = 0; kt < 16; kt += 2) {
        storeA(0, va); storeB(0, wa);
        loadA(kt + 1, vb); loadB(kt + 1, wb);
        __syncthreads();
        mfmaTile(0);
        storeA(1, vb); storeB(1, wb);
        if (kt + 2 < 16) { loadA(kt + 2, va); loadB(kt + 2, wa); }
        __syncthreads();
        mfmaTile(1);
    }

    {
        int mrow = n0 + wave * 16 + quad * 4;
#pragma unroll
        for (int r = 0; r < 4; r++) {
            int n = mrow + r;
            if (n < N_NODES) {
#pragma unroll
                for (int nt = 0; nt < 8; nt++)
                    out[((long)nt * N_NODES + n) * 16 + l16] = (unsigned short)f2bf(acc[nt][r]);
            }
        }
    }
}

// ---------------------------------------------------------------------------
// MFMA GEMM 3 (layer 1 + W_out folded): z = Basis(h) @ C2W  [N x 512]@[512 x 16]
// Reads h ROW-major (spmm output). Unchanged.
// ---------------------------------------------------------------------------
__global__ __launch_bounds__(256, 4) void cheb16_gemm(const unsigned short* __restrict__ h,
                                                      const unsigned short* __restrict__ C2W,
                                                      float* __restrict__ z) {
    __shared__ __align__(16) short As[2][64][40];
    __shared__ __align__(16) short Bs16[16][520];
    const int tid  = threadIdx.x;
    const int lane = tid & 63;
    const int wave = tid >> 6;
    const int quad = lane >> 4;
    const int l16  = lane & 15;
    const int n0   = blockIdx.x * 64;
    const int ar   = tid >> 2;
    const int sub  = tid & 3;

    {
        int o16 = tid >> 4;
        int seg = tid & 15;
        *(bf16x8*)&Bs16[o16][seg * 32]      = *(const bf16x8*)&C2W[o16 * 512 + seg * 32];
        *(bf16x8*)&Bs16[o16][seg * 32 + 8]  = *(const bf16x8*)&C2W[o16 * 512 + seg * 32 + 8];
        *(bf16x8*)&Bs16[o16][seg * 32 + 16] = *(const bf16x8*)&C2W[o16 * 512 + seg * 32 + 16];
        *(bf16x8*)&Bs16[o16][seg * 32 + 24] = *(const bf16x8*)&C2W[o16 * 512 + seg * 32 + 24];
    }

    int nA = n0 + ar; if (nA >= N_NODES) nA = N_NODES - 1;
    const unsigned short* __restrict__ hrow = h + (long)nA * HID;

    f32x4 acc;
#pragma unroll
    for (int r = 0; r < 4; r++) acc[r] = 0.f;

    auto loadA = [&](int kt, unsigned& v) {
        v = *(const unsigned*)(hrow + kt * 8 + sub * 2);
    };
    auto storeA = [&](int buf, unsigned v) {
        float hx[2] = {bf_lo(v), bf_hi(v)};
        short t[8];
#pragma unroll
        for (int q = 0; q < 2; q++) {
            float xx = fminf(fmaxf(hx[q], -15.f), 15.f);
            float e  = __expf(2.f * xx);
            float tt = (e - 1.f) / (e + 1.f);
            float T2 = 2.f * tt * tt - 1.f;
            float T3 = 2.f * tt * T2 - tt;
            t[q * 4 + 0] = (short)0x3F80;
            t[q * 4 + 1] = f2bf(tt);
            t[q * 4 + 2] = f2bf(T2);
            t[q * 4 + 3] = f2bf(T3);
        }
        *(bf16x8*)&As[buf][ar][sub * 8] = *(bf16x8*)&t[0];
    };
    auto mfmaTile = [&](int buf, int kt) {
        bf16x8 a = *(const bf16x8*)&As[buf][wave * 16 + l16][quad * 8];
        bf16x8 b = *(const bf16x8*)&Bs16[l16][kt * 32 + quad * 8];
        acc = __builtin_amdgcn_mfma_f32_16x16x32_bf16(a, b, acc, 0, 0, 0);
    };

    unsigned va, vb;
    loadA(0, va);
    for (int kt = 0; kt < 16; kt += 2) {
        storeA(0, va);
        loadA(kt + 1, vb);
        __syncthreads();
        mfmaTile(0, kt);
        storeA(1, vb);
        if (kt + 2 < 16) loadA(kt + 2, va);
        __syncthreads();
        mfmaTile(1, kt + 1);
    }

    {
        int mrow = n0 + wave * 16 + quad * 4;
#pragma unroll
        for (int r = 0; r < 4; r++) {
            int n = mrow + r;
            if (n < N_NODES) z[n * 16 + l16] = acc[r];
        }
    }
}

// ---------------------------------------------------------------------------
// SpMM, XCD-sliced: slice = blockIdx.x & 7 (round-robin block->XCD dispatch
// pins each 3.2 MB h-slice into one XCD's 4 MiB L2). h is SLICE-MAJOR
// [8][N][16] bf16; output is ROW-major [N][128] bf16 for the consumer GEMM.
// Wave = 1 row: 16 edge slots x 4 lanes x uint2 (8 B = 4 bf16 features).
// ---------------------------------------------------------------------------
__global__ __launch_bounds__(256) void spmm_sliced(const int* __restrict__ row_start,
                                                   const int* __restrict__ col_sorted,
                                                   const unsigned short* __restrict__ h_sm,
                                                   unsigned short* __restrict__ out) {
    const int s    = blockIdx.x & 7;                                  // slice / XCD
    const int wid  = (((blockIdx.x >> 3) * 256) + (int)threadIdx.x) >> 6;  // row
    const int lane = threadIdx.x & 63;
    const int sub  = lane >> 2;      // edge slot 0..15
    const int fl   = lane & 3;       // uint2 slot within 16-feature slice
    if (wid >= N_NODES) return;
    const int rs = row_start[wid];
    const int re = row_start[wid + 1];
    const uint2* __restrict__ hs = (const uint2*)h_sm + (long)s * N_NODES * 4;

    float a0 = 0.f, a1 = 0.f, a2 = 0.f, a3 = 0.f;

    int j = rs;
    for (; j + 16 <= re; j += 16) {
        int c = col_sorted[j + sub];
        uint2 u = hs[c * 4 + fl];
        a0 += bf_lo(u.x); a1 += bf_hi(u.x);
        a2 += bf_lo(u.y); a3 += bf_hi(u.y);
    }
    if (j < re) {
        int idx = j + sub;
        float m = (idx < re) ? 1.f : 0.f;
        int ci  = (idx < re) ? idx : (re - 1);
        int c = col_sorted[ci];
        uint2 u = hs[c * 4 + fl];
        a0 = fmaf(m, bf_lo(u.x), a0); a1 = fmaf(m, bf_hi(u.x), a1);
        a2 = fmaf(m, bf_lo(u.y), a2); a3 = fmaf(m, bf_hi(u.y), a3);
    }
#pragma unroll
    for (int mm = 4; mm <= 32; mm <<= 1) {
        a0 += __shfl_xor(a0, mm);
        a1 += __shfl_xor(a1, mm);
        a2 += __shfl_xor(a2, mm);
        a3 += __shfl_xor(a3, mm);
    }
    if (sub == 0) {
        uint2 pw;
        pw.x = (unsigned)(unsigned short)f2bf(a0) | ((unsigned)(unsigned short)f2bf(a1) << 16);
        pw.y = (unsigned)(unsigned short)f2bf(a2) | ((unsigned)(unsigned short)f2bf(a3) << 16);
        *(uint2*)&out[(long)wid * HID + s * 16 + fl * 4] = pw;
    }
}

// ---------------------------------------------------------------------------
// Final spmm (16-wide f32) + log_softmax fused (unchanged)
// ---------------------------------------------------------------------------
__global__ __launch_bounds__(256) void spmm_out(const int* __restrict__ row_start,
                                                const int* __restrict__ col_sorted,
                                                const float* __restrict__ z,
                                                float* __restrict__ out) {
    const int wid  = (blockIdx.x * 256 + threadIdx.x) >> 6;
    const int lane = threadIdx.x & 63;
    const int sub  = lane >> 4;
    const int fl   = lane & 15;
    if (wid >= N_NODES) return;
    const int s = row_start[wid];
    const int e = row_start[wid + 1];

    float a0 = 0.f, a1 = 0.f;
    int j = s;
    for (; j + 8 <= e; j += 8) {
        int c0 = col_sorted[j + sub];
        int c1 = col_sorted[j + 4 + sub];
        a0 += z[c0 * 16 + fl];
        a1 += z[c1 * 16 + fl];
    }
    for (; j < e; j += 4) {
        int idx = j + sub;
        float m = (idx < e) ? 1.f : 0.f;
        int ci = (idx < e) ? idx : (e - 1);
        a0 = fmaf(m, z[col_sorted[ci] * 16 + fl], a0);
    }
    float v = a0 + a1;
    v += __shfl_xor(v, 16);
    v += __shfl_xor(v, 32);
    float mx = v;
#pragma unroll
    for (int m = 8; m >= 1; m >>= 1) mx = fmaxf(mx, __shfl_xor(mx, m));
    float ex = expf(v - mx);
    float se = ex;
#pragma unroll
    for (int m = 8; m >= 1; m >>= 1) se += __shfl_xor(se, m);
    if (sub == 0) out[wid * 16 + fl] = v - mx - logf(se);
}

// ---------------------------------------------------------------------------

extern "C" void kernel_launch(void* const* d_in, const int* in_sizes, int n_in,
                              void* d_out, int out_size, void* d_ws, size_t ws_size,
                              hipStream_t stream) {
    const float* x     = (const float*)d_in[0];
    const int*   ei    = (const int*)d_in[1];
    const float* W_in  = (const float*)d_in[2];
    const float* cheb  = (const float*)d_in[3];
    const float* W_out = (const float*)d_in[4];
    float* out = (float*)d_out;

    char* p = (char*)d_ws;
    unsigned short* hA   = (unsigned short*)p; p += (size_t)N_NODES * HID * 2;   // 25.6 MB (slice-major)
    unsigned short* hB   = (unsigned short*)p; p += (size_t)N_NODES * HID * 2;   // 25.6 MB (row/slice-major per stage)
    int*   col_sorted    = (int*)p;            p += (size_t)N_EDGES * 4;         // 6.4 MB
    unsigned short* Bmat = (unsigned short*)p; p += (size_t)HID * KDIM * 2;      // 128 KB (layer-0)
    unsigned short* Wmat = (unsigned short*)p; p += (size_t)HID * KDIM * 2;      // 128 KB
    unsigned short* C2W  = (unsigned short*)p; p += (size_t)16 * KDIM * 2;       // 16 KB
    float* zbuf          = (float*)p;          p += (size_t)N_NODES * 16 * 4;    // 6.4 MB
    int*   row_start     = (int*)p;            p += (size_t)(N_NODES + 1) * 4;
    int*   bcnt          = (int*)p;            p += (size_t)NB * 16 * 4;         // 50 KB
    int*   bbase         = (int*)p;            p += (size_t)NB * 4;

    // bucket buffer aliases hA (dead until gemm_xw): 782*4096*4 = 12.8 MB < 25.6 MB
    unsigned* bbuf = (unsigned*)hA;

    const int nblk_gemm  = (N_NODES + 63) / 64;         // 1563
    const int nblk_edge  = N_EDGES / 256;               // 6250
    const int nblk_spmm  = (N_NODES + 3) / 4;           // 25000
    const int nblk_spmm8 = nblk_spmm * 8;               // 200000 (8 slices)

    hipMemsetAsync(bcnt, 0, (size_t)NB * 16 * 4, stream);
    bin_kernel<<<nblk_edge, 256, 0, stream>>>(ei, bcnt, bbuf);
    bscan_kernel<<<1, 1024, 0, stream>>>(bcnt, bbase);
    place_kernel<<<NB, 256, 0, stream>>>(bbuf, bcnt, bbase, row_start, col_sorted);
    repack_cheb<<<HID * KDIM / 256, 256, 0, stream>>>(cheb, Bmat);
    repack_w<<<HID * KDIM / 256, 256, 0, stream>>>(W_in, Wmat);
    repack_c2w<<<16 * KDIM / 256, 256, 0, stream>>>(cheb, W_out, C2W);

    gemm_xw<<<nblk_gemm, 256, 0, stream>>>(x, Wmat, hA);                          // -> slice-major hA
    spmm_sliced<<<nblk_spmm8, 256, 0, stream>>>(row_start, col_sorted, hA, hB);   // -> row-major hB

    cheb_gemm<<<nblk_gemm, 256, 0, stream>>>(hB, Bmat, hA);                       // -> slice-major hA
    spmm_sliced<<<nblk_spmm8, 256, 0, stream>>>(row_start, col_sorted, hA, hB);   // -> row-major hB

    cheb16_gemm<<<nblk_gemm, 256, 0, stream>>>(hB, C2W, zbuf);                    // layer 1 + W_out
    spmm_out<<<nblk_spmm, 256, 0, stream>>>(row_start, col_sorted, zbuf, out);    // spmm + lsm
}

// Round 8
// 645.408 us; speedup vs baseline: 1.4096x; 1.4096x over previous
//
#include <hip/hip_runtime.h>
#include <hip/hip_bf16.h>

#define N_NODES 100000
#define N_EDGES 1600000
#define IN_DIM  500
#define HID     128
#define KDIM    512   // HID * (DEG+1)
#define NB      782   // ceil(N_NODES/128) buckets
#define BCAP    4096  // bucket capacity (expected 2046, >20 sigma headroom)

typedef __attribute__((ext_vector_type(8))) short bf16x8;
typedef __attribute__((ext_vector_type(4))) float f32x4;

__device__ inline short f2bf(float x) {
    union { float f; unsigned u; } v; v.f = x;
    unsigned r = (v.u + 0x7FFFu + ((v.u >> 16) & 1u)) >> 16;  // RNE
    return (short)r;
}
__device__ inline float bf_lo(unsigned u) { union { unsigned u; float f; } v; v.u = u << 16; return v.f; }
__device__ inline float bf_hi(unsigned u) { union { unsigned u; float f; } v; v.u = u & 0xFFFF0000u; return v.f; }

// Chebyshev basis from 2 packed bf16 features -> 8 bf16 A-fragment
__device__ inline bf16x8 cheb_frag(unsigned v) {
    float hx[2] = {bf_lo(v), bf_hi(v)};
    short t[8];
#pragma unroll
    for (int q = 0; q < 2; q++) {
        float xx = fminf(fmaxf(hx[q], -15.f), 15.f);
        float e  = __expf(2.f * xx);
        float tt = (e - 1.f) / (e + 1.f);     // tanh
        float T2 = 2.f * tt * tt - 1.f;
        float T3 = 2.f * tt * T2 - tt;
        t[q * 4 + 0] = (short)0x3F80;         // bf16(1.0)
        t[q * 4 + 1] = f2bf(tt);
        t[q * 4 + 2] = f2bf(T2);
        t[q * 4 + 3] = f2bf(T3);
    }
    return *(bf16x8*)&t[0];
}

// ---------------------------------------------------------------------------
// CSR build, two-pass binned (unchanged)
// ---------------------------------------------------------------------------

__global__ __launch_bounds__(256) void bin_kernel(const int* __restrict__ ei,
                                                  int* __restrict__ bcnt,
                                                  unsigned* __restrict__ buf) {
    int e = blockIdx.x * 256 + threadIdx.x;
    if (e < N_EDGES) {
        int r = ei[e];
        int c = ei[N_EDGES + e];
        int b = r >> 7;
        int p = atomicAdd(&bcnt[b * 16], 1);   // stride 64 B: spread L2 slices
        if (p < BCAP) buf[b * BCAP + p] = ((unsigned)(r & 127) << 17) | (unsigned)c;
    }
}

__global__ __launch_bounds__(1024) void bscan_kernel(const int* __restrict__ bcnt,
                                                     int* __restrict__ bbase) {
    __shared__ int buf[1024];
    const int tid = threadIdx.x;
    int v = (tid < NB) ? bcnt[tid * 16] : 0;
    buf[tid] = v;
    __syncthreads();
    for (int off = 1; off < 1024; off <<= 1) {
        int t = (tid >= off) ? buf[tid - off] : 0;
        __syncthreads();
        buf[tid] += t;
        __syncthreads();
    }
    if (tid < NB) bbase[tid] = buf[tid] - v;   // exclusive
}

__global__ __launch_bounds__(256) void place_kernel(const unsigned* __restrict__ buf,
                                                    const int* __restrict__ bcnt,
                                                    const int* __restrict__ bbase,
                                                    int* __restrict__ row_start,
                                                    int* __restrict__ col_sorted) {
    __shared__ int hist[128];
    __shared__ int scan[128];
    __shared__ int cur[128];
    const int b = blockIdx.x, tid = threadIdx.x;
    int cnt = bcnt[b * 16]; if (cnt > BCAP) cnt = BCAP;
    const int base = bbase[b];
    if (tid < 128) hist[tid] = 0;
    __syncthreads();
    for (int i = tid; i < cnt; i += 256)
        atomicAdd(&hist[buf[b * BCAP + i] >> 17], 1);
    __syncthreads();
    if (tid < 128) scan[tid] = hist[tid];
    __syncthreads();
    for (int off = 1; off < 128; off <<= 1) {
        int t = (tid < 128 && tid >= off) ? scan[tid - off] : 0;
        __syncthreads();
        if (tid < 128) scan[tid] += t;
        __syncthreads();
    }
    if (tid < 128) {
        int excl = scan[tid] - hist[tid] + base;
        cur[tid] = excl;
        int r = b * 128 + tid;
        if (r < N_NODES) row_start[r] = excl;
        if (r == N_NODES - 1) row_start[N_NODES] = excl + hist[tid];
    }
    __syncthreads();
    for (int i = tid; i < cnt; i += 256) {
        unsigned u = buf[b * BCAP + i];
        int rl = (int)(u >> 17);
        int c  = (int)(u & 0x1FFFFu);
        int pos = atomicAdd(&cur[rl], 1);
        col_sorted[pos] = c;
    }
}

// ---------------------------------------------------------------------------
// Merged repacks (once per launch): blocks [0,256) -> Bmat, [256,512) -> Wmat,
// [512,544) -> C2W. Saves 2 launches.
// ---------------------------------------------------------------------------
__global__ __launch_bounds__(256) void repack_all(const float* __restrict__ cheb,
                                                  const float* __restrict__ W,
                                                  const float* __restrict__ Wout,
                                                  unsigned short* __restrict__ Bmat,
                                                  unsigned short* __restrict__ Wmat,
                                                  unsigned short* __restrict__ C2W) {
    const int b = blockIdx.x;
    if (b < 256) {
        int idx = b * 256 + threadIdx.x;       // < 128*512
        int o = idx >> 9;
        int k = idx & 511;
        int i = k >> 2;
        int d = k & 3;
        Bmat[idx] = (unsigned short)f2bf(cheb[i * 512 + o * 4 + d]);
    } else if (b < 512) {
        int idx = (b - 256) * 256 + threadIdx.x;
        int o = idx >> 9;
        int k = idx & 511;
        Wmat[idx] = (k < IN_DIM) ? (unsigned short)f2bf(W[k * HID + o]) : 0;
    } else {
        int idx = (b - 512) * 256 + threadIdx.x;   // < 16*512
        int o16 = idx >> 9;
        int k   = idx & 511;
        const float* cb = cheb + 65536 + (k >> 2) * 512 + (k & 3);
        float s = 0.f;
#pragma unroll 4
        for (int o = 0; o < 128; o++) s += cb[o * 4] * Wout[o * 16 + o16];
        C2W[o16 * 512 + k] = (unsigned short)f2bf(s);
    }
}

// ---------------------------------------------------------------------------
// MFMA GEMM 1: h = x @ W_in  [100000 x 500(512)] @ [500 x 128] -> bf16
// 64x128 tile. A-operand DIRECT global->reg (no LDS): each lane loads its own
// MFMA fragment rows (wave coalesces to 128 B/row per kt). Only B is LDS-
// staged (dbuf). Barriers guard B only. Row-major output.
// ---------------------------------------------------------------------------
__global__ __launch_bounds__(256, 4) void gemm_xw(const float* __restrict__ x,
                                                  const unsigned short* __restrict__ Wmat,
                                                  unsigned short* __restrict__ out) {
    __shared__ __align__(16) short Bs[2][128][40];   // 20.5 KB
    const int tid  = threadIdx.x;
    const int lane = tid & 63;
    const int wave = tid >> 6;
    const int quad = lane >> 4;
    const int l16  = lane & 15;
    const int n0   = blockIdx.x * 64;
    const int br   = tid >> 1;     // B row 0..127
    const int bh   = tid & 1;      // 16-short segment

    int row = n0 + wave * 16 + l16; if (row >= N_NODES) row = N_NODES - 1;
    const float* __restrict__ xrow = x + (long)row * IN_DIM;

    f32x4 acc[8];
#pragma unroll
    for (int nt = 0; nt < 8; nt++)
#pragma unroll
        for (int r = 0; r < 4; r++) acc[nt][r] = 0.f;

    auto loadA = [&](int kt, float (&v)[8]) {
        const int kb = kt * 32 + quad * 8;
        if (kb + 8 <= IN_DIM) {
            const float4* s4 = (const float4*)(xrow + kb);
            float4 a0 = s4[0], a1 = s4[1];
            v[0]=a0.x; v[1]=a0.y; v[2]=a0.z; v[3]=a0.w;
            v[4]=a1.x; v[5]=a1.y; v[6]=a1.z; v[7]=a1.w;
        } else {
#pragma unroll
            for (int q = 0; q < 8; q++) v[q] = (kb + q < IN_DIM) ? xrow[kb + q] : 0.f;
        }
    };
    auto loadB = [&](int kt, bf16x8 (&w)[2]) {
        w[0] = *(const bf16x8*)&Wmat[br * 512 + kt * 32 + bh * 16];
        w[1] = *(const bf16x8*)&Wmat[br * 512 + kt * 32 + bh * 16 + 8];
    };
    auto storeB = [&](int buf, const bf16x8 (&w)[2]) {
        *(bf16x8*)&Bs[buf][br][bh * 16]     = w[0];
        *(bf16x8*)&Bs[buf][br][bh * 16 + 8] = w[1];
    };
    auto mfmaTile = [&](int buf, const float (&v)[8]) {
        short t[8];
#pragma unroll
        for (int q = 0; q < 8; q++) t[q] = f2bf(v[q]);
        bf16x8 a = *(bf16x8*)&t[0];
#pragma unroll
        for (int nt = 0; nt < 8; nt++) {
            bf16x8 b = *(const bf16x8*)&Bs[buf][nt * 16 + l16][quad * 8];
            acc[nt] = __builtin_amdgcn_mfma_f32_16x16x32_bf16(a, b, acc[nt], 0, 0, 0);
        }
    };

    float  va[8], vb[8];
    bf16x8 wa[2], wb[2];
    loadA(0, va); loadB(0, wa);
    for (int kt = 0; kt < 16; kt += 2) {
        storeB(0, wa);
        loadB(kt + 1, wb);
        loadA(kt + 1, vb);
        __syncthreads();
        mfmaTile(0, va);
        storeB(1, wb);
        if (kt + 2 < 16) { loadB(kt + 2, wa); loadA(kt + 2, va); }
        __syncthreads();
        mfmaTile(1, vb);
    }

    {
        int mrow = n0 + wave * 16 + quad * 4;
#pragma unroll
        for (int r = 0; r < 4; r++) {
            int n = mrow + r;
            if (n < N_NODES) {
#pragma unroll
                for (int nt = 0; nt < 8; nt++)
                    out[(long)n * HID + nt * 16 + l16] = (unsigned short)f2bf(acc[nt][r]);
            }
        }
    }
}

// ---------------------------------------------------------------------------
// MFMA GEMM 2 (layer 0): out = Basis(h) @ C1  [N x 512]@[512 x 128]
// A-operand: each lane preloads its 16 packed-bf16 h-chunks (64 B) upfront,
// computes the tanh-basis fragment in registers per kt. No A LDS. B dbuf'd.
// ---------------------------------------------------------------------------
__global__ __launch_bounds__(256, 4) void cheb_gemm(const unsigned short* __restrict__ h,
                                                    const unsigned short* __restrict__ Bmat,
                                                    unsigned short* __restrict__ out) {
    __shared__ __align__(16) short Bs[2][128][40];
    const int tid  = threadIdx.x;
    const int lane = tid & 63;
    const int wave = tid >> 6;
    const int quad = lane >> 4;
    const int l16  = lane & 15;
    const int n0   = blockIdx.x * 64;
    const int br   = tid >> 1;
    const int bh   = tid & 1;

    int row = n0 + wave * 16 + l16; if (row >= N_NODES) row = N_NODES - 1;
    const unsigned short* __restrict__ hrow = h + (long)row * HID;

    // Upfront A source: feature pair (kt*8 + quad*2) for all kt.
    unsigned hreg[16];
#pragma unroll
    for (int kt = 0; kt < 16; kt++)
        hreg[kt] = *(const unsigned*)(hrow + kt * 8 + quad * 2);

    f32x4 acc[8];
#pragma unroll
    for (int nt = 0; nt < 8; nt++)
#pragma unroll
        for (int r = 0; r < 4; r++) acc[nt][r] = 0.f;

    auto loadB = [&](int kt, bf16x8 (&w)[2]) {
        w[0] = *(const bf16x8*)&Bmat[br * 512 + kt * 32 + bh * 16];
        w[1] = *(const bf16x8*)&Bmat[br * 512 + kt * 32 + bh * 16 + 8];
    };
    auto storeB = [&](int buf, const bf16x8 (&w)[2]) {
        *(bf16x8*)&Bs[buf][br][bh * 16]     = w[0];
        *(bf16x8*)&Bs[buf][br][bh * 16 + 8] = w[1];
    };
    auto mfmaTile = [&](int buf, int kt) {
        bf16x8 a = cheb_frag(hreg[kt]);
#pragma unroll
        for (int nt = 0; nt < 8; nt++) {
            bf16x8 b = *(const bf16x8*)&Bs[buf][nt * 16 + l16][quad * 8];
            acc[nt] = __builtin_amdgcn_mfma_f32_16x16x32_bf16(a, b, acc[nt], 0, 0, 0);
        }
    };

    bf16x8 wa[2], wb[2];
    loadB(0, wa);
    for (int kt = 0; kt < 16; kt += 2) {
        storeB(0, wa);
        loadB(kt + 1, wb);
        __syncthreads();
        mfmaTile(0, kt);
        storeB(1, wb);
        if (kt + 2 < 16) loadB(kt + 2, wa);
        __syncthreads();
        mfmaTile(1, kt + 1);
    }

    {
        int mrow = n0 + wave * 16 + quad * 4;
#pragma unroll
        for (int r = 0; r < 4; r++) {
            int n = mrow + r;
            if (n < N_NODES) {
#pragma unroll
                for (int nt = 0; nt < 8; nt++)
                    out[(long)n * HID + nt * 16 + l16] = (unsigned short)f2bf(acc[nt][r]);
            }
        }
    }
}

// ---------------------------------------------------------------------------
// MFMA GEMM 3 (layer 1 + W_out folded): z = Basis(h) @ C2W  [N x 512]@[512 x 16]
// B LDS-resident (16 KB, staged once). A in registers (upfront h preload +
// per-kt basis). ONE barrier total — zero in-loop syncs.
// ---------------------------------------------------------------------------
__global__ __launch_bounds__(256, 4) void cheb16_gemm(const unsigned short* __restrict__ h,
                                                      const unsigned short* __restrict__ C2W,
                                                      float* __restrict__ z) {
    __shared__ __align__(16) short Bs16[16][520];
    const int tid  = threadIdx.x;
    const int lane = tid & 63;
    const int wave = tid >> 6;
    const int quad = lane >> 4;
    const int l16  = lane & 15;
    const int n0   = blockIdx.x * 64;

    {
        int o16 = tid >> 4;
        int seg = tid & 15;
        *(bf16x8*)&Bs16[o16][seg * 32]      = *(const bf16x8*)&C2W[o16 * 512 + seg * 32];
        *(bf16x8*)&Bs16[o16][seg * 32 + 8]  = *(const bf16x8*)&C2W[o16 * 512 + seg * 32 + 8];
        *(bf16x8*)&Bs16[o16][seg * 32 + 16] = *(const bf16x8*)&C2W[o16 * 512 + seg * 32 + 16];
        *(bf16x8*)&Bs16[o16][seg * 32 + 24] = *(const bf16x8*)&C2W[o16 * 512 + seg * 32 + 24];
    }

    int row = n0 + wave * 16 + l16; if (row >= N_NODES) row = N_NODES - 1;
    const unsigned short* __restrict__ hrow = h + (long)row * HID;

    unsigned hreg[16];
#pragma unroll
    for (int kt = 0; kt < 16; kt++)
        hreg[kt] = *(const unsigned*)(hrow + kt * 8 + quad * 2);

    f32x4 acc;
#pragma unroll
    for (int r = 0; r < 4; r++) acc[r] = 0.f;

    __syncthreads();   // B ready; the only barrier

#pragma unroll
    for (int kt = 0; kt < 16; kt++) {
        bf16x8 a = cheb_frag(hreg[kt]);
        bf16x8 b = *(const bf16x8*)&Bs16[l16][kt * 32 + quad * 8];
        acc = __builtin_amdgcn_mfma_f32_16x16x32_bf16(a, b, acc, 0, 0, 0);
    }

    {
        int mrow = n0 + wave * 16 + quad * 4;
#pragma unroll
        for (int r = 0; r < 4; r++) {
            int n = mrow + r;
            if (n < N_NODES) z[n * 16 + l16] = acc[r];
        }
    }
}

// ---------------------------------------------------------------------------
// SpMM gather (128-wide bf16, ROW-major h): wave/row; 16 lanes x uint4 per
// edge, 4 edges/instr, unrolled x2. (reverted to the 653 µs baseline form)
// ---------------------------------------------------------------------------
__global__ __launch_bounds__(256) void spmm_gather(const int* __restrict__ row_start,
                                                   const int* __restrict__ col_sorted,
                                                   const unsigned short* __restrict__ h,
                                                   unsigned short* __restrict__ out) {
    const int wid  = (blockIdx.x * 256 + threadIdx.x) >> 6;   // row
    const int lane = threadIdx.x & 63;
    const int sub  = lane >> 4;        // edge slot 0..3
    const int fl   = lane & 15;        // 16-byte feature slice 0..15
    if (wid >= N_NODES) return;
    const int s = row_start[wid];
    const int e = row_start[wid + 1];
    const uint4* __restrict__ h4 = (const uint4*)h;   // one row = 16 uint4

    float a[8], b[8];
#pragma unroll
    for (int q = 0; q < 8; q++) { a[q] = 0.f; b[q] = 0.f; }

    int j = s;
    for (; j + 8 <= e; j += 8) {
        int c0 = col_sorted[j + sub];
        int c1 = col_sorted[j + 4 + sub];
        uint4 u0 = h4[c0 * 16 + fl];
        uint4 u1 = h4[c1 * 16 + fl];
        a[0] += bf_lo(u0.x); a[1] += bf_hi(u0.x);
        a[2] += bf_lo(u0.y); a[3] += bf_hi(u0.y);
        a[4] += bf_lo(u0.z); a[5] += bf_hi(u0.z);
        a[6] += bf_lo(u0.w); a[7] += bf_hi(u0.w);
        b[0] += bf_lo(u1.x); b[1] += bf_hi(u1.x);
        b[2] += bf_lo(u1.y); b[3] += bf_hi(u1.y);
        b[4] += bf_lo(u1.z); b[5] += bf_hi(u1.z);
        b[6] += bf_lo(u1.w); b[7] += bf_hi(u1.w);
    }
    for (; j < e; j += 4) {
        int idx = j + sub;
        float m = (idx < e) ? 1.f : 0.f;
        int ci = (idx < e) ? idx : (e - 1);
        int c = col_sorted[ci];
        uint4 u = h4[c * 16 + fl];
        a[0] = fmaf(m, bf_lo(u.x), a[0]); a[1] = fmaf(m, bf_hi(u.x), a[1]);
        a[2] = fmaf(m, bf_lo(u.y), a[2]); a[3] = fmaf(m, bf_hi(u.y), a[3]);
        a[4] = fmaf(m, bf_lo(u.z), a[4]); a[5] = fmaf(m, bf_hi(u.z), a[5]);
        a[6] = fmaf(m, bf_lo(u.w), a[6]); a[7] = fmaf(m, bf_hi(u.w), a[7]);
    }
#pragma unroll
    for (int q = 0; q < 8; q++) a[q] += b[q];
#pragma unroll
    for (int q = 0; q < 8; q++) {
        a[q] += __shfl_xor(a[q], 16);
        a[q] += __shfl_xor(a[q], 32);
    }
    if (sub == 0) {
        unsigned w0 = (unsigned)(unsigned short)f2bf(a[0]) | ((unsigned)(unsigned short)f2bf(a[1]) << 16);
        unsigned w1 = (unsigned)(unsigned short)f2bf(a[2]) | ((unsigned)(unsigned short)f2bf(a[3]) << 16);
        unsigned w2 = (unsigned)(unsigned short)f2bf(a[4]) | ((unsigned)(unsigned short)f2bf(a[5]) << 16);
        unsigned w3 = (unsigned)(unsigned short)f2bf(a[6]) | ((unsigned)(unsigned short)f2bf(a[7]) << 16);
        uint4 pw; pw.x = w0; pw.y = w1; pw.z = w2; pw.w = w3;
        ((uint4*)out)[wid * 16 + fl] = pw;
    }
}

// ---------------------------------------------------------------------------
// Final spmm (16-wide f32) + log_softmax fused (unchanged)
// ---------------------------------------------------------------------------
__global__ __launch_bounds__(256) void spmm_out(const int* __restrict__ row_start,
                                                const int* __restrict__ col_sorted,
                                                const float* __restrict__ z,
                                                float* __restrict__ out) {
    const int wid  = (blockIdx.x * 256 + threadIdx.x) >> 6;
    const int lane = threadIdx.x & 63;
    const int sub  = lane >> 4;
    const int fl   = lane & 15;
    if (wid >= N_NODES) return;
    const int s = row_start[wid];
    const int e = row_start[wid + 1];

    float a0 = 0.f, a1 = 0.f;
    int j = s;
    for (; j + 8 <= e; j += 8) {
        int c0 = col_sorted[j + sub];
        int c1 = col_sorted[j + 4 + sub];
        a0 += z[c0 * 16 + fl];
        a1 += z[c1 * 16 + fl];
    }
    for (; j < e; j += 4) {
        int idx = j + sub;
        float m = (idx < e) ? 1.f : 0.f;
        int ci = (idx < e) ? idx : (e - 1);
        a0 = fmaf(m, z[col_sorted[ci] * 16 + fl], a0);
    }
    float v = a0 + a1;
    v += __shfl_xor(v, 16);
    v += __shfl_xor(v, 32);
    float mx = v;
#pragma unroll
    for (int m = 8; m >= 1; m >>= 1) mx = fmaxf(mx, __shfl_xor(mx, m));
    float ex = expf(v - mx);
    float se = ex;
#pragma unroll
    for (int m = 8; m >= 1; m >>= 1) se += __shfl_xor(se, m);
    if (sub == 0) out[wid * 16 + fl] = v - mx - logf(se);
}

// ---------------------------------------------------------------------------

extern "C" void kernel_launch(void* const* d_in, const int* in_sizes, int n_in,
                              void* d_out, int out_size, void* d_ws, size_t ws_size,
                              hipStream_t stream) {
    const float* x     = (const float*)d_in[0];
    const int*   ei    = (const int*)d_in[1];
    const float* W_in  = (const float*)d_in[2];
    const float* cheb  = (const float*)d_in[3];
    const float* W_out = (const float*)d_in[4];
    float* out = (float*)d_out;

    char* p = (char*)d_ws;
    unsigned short* hA   = (unsigned short*)p; p += (size_t)N_NODES * HID * 2;   // 25.6 MB
    unsigned short* hB   = (unsigned short*)p; p += (size_t)N_NODES * HID * 2;   // 25.6 MB
    int*   col_sorted    = (int*)p;            p += (size_t)N_EDGES * 4;         // 6.4 MB
    unsigned short* Bmat = (unsigned short*)p; p += (size_t)HID * KDIM * 2;      // 128 KB (layer-0)
    unsigned short* Wmat = (unsigned short*)p; p += (size_t)HID * KDIM * 2;      // 128 KB
    unsigned short* C2W  = (unsigned short*)p; p += (size_t)16 * KDIM * 2;       // 16 KB
    float* zbuf          = (float*)p;          p += (size_t)N_NODES * 16 * 4;    // 6.4 MB
    int*   row_start     = (int*)p;            p += (size_t)(N_NODES + 1) * 4;
    int*   bcnt          = (int*)p;            p += (size_t)NB * 16 * 4;         // 50 KB
    int*   bbase         = (int*)p;            p += (size_t)NB * 4;

    // bucket buffer aliases hA (dead until gemm_xw): 782*4096*4 = 12.8 MB < 25.6 MB
    unsigned* bbuf = (unsigned*)hA;

    const int nblk_gemm = (N_NODES + 63) / 64;         // 1563
    const int nblk_edge = N_EDGES / 256;               // 6250
    const int nblk_spmm = (N_NODES + 3) / 4;           // 25000

    hipMemsetAsync(bcnt, 0, (size_t)NB * 16 * 4, stream);
    bin_kernel<<<nblk_edge, 256, 0, stream>>>(ei, bcnt, bbuf);
    bscan_kernel<<<1, 1024, 0, stream>>>(bcnt, bbase);
    place_kernel<<<NB, 256, 0, stream>>>(bbuf, bcnt, bbase, row_start, col_sorted);
    repack_all<<<544, 256, 0, stream>>>(cheb, W_in, W_out, Bmat, Wmat, C2W);

    gemm_xw<<<nblk_gemm, 256, 0, stream>>>(x, Wmat, hA);
    spmm_gather<<<nblk_spmm, 256, 0, stream>>>(row_start, col_sorted, hA, hB);

    cheb_gemm<<<nblk_gemm, 256, 0, stream>>>(hB, Bmat, hA);                    // layer 0
    spmm_gather<<<nblk_spmm, 256, 0, stream>>>(row_start, col_sorted, hA, hB);

    cheb16_gemm<<<nblk_gemm, 256, 0, stream>>>(hB, C2W, zbuf);                 // layer 1 + W_out
    spmm_out<<<nblk_spmm, 256, 0, stream>>>(row_start, col_sorted, zbuf, out); // spmm + lsm
}

// Round 11
// 625.973 us; speedup vs baseline: 1.4533x; 1.0310x over previous
//
#include <hip/hip_runtime.h>
#include <hip/hip_bf16.h>

#define N_NODES 100000
#define N_EDGES 1600000
#define IN_DIM  500
#define HID     128
#define KDIM    512   // HID * (DEG+1)
#define NB      782   // ceil(N_NODES/128) buckets
#define BCAP    4096  // bucket capacity (expected 2046, >20 sigma headroom)

#define NG_GEMM 1563  // gemm_xw blocks
#define NG_BIN  6250  // bin blocks

typedef __attribute__((ext_vector_type(8))) short bf16x8;
typedef __attribute__((ext_vector_type(4))) float f32x4;

__device__ inline short f2bf(float x) {
    union { float f; unsigned u; } v; v.f = x;
    unsigned r = (v.u + 0x7FFFu + ((v.u >> 16) & 1u)) >> 16;  // RNE
    return (short)r;
}
__device__ inline float bf_lo(unsigned u) { union { unsigned u; float f; } v; v.u = u << 16; return v.f; }
__device__ inline float bf_hi(unsigned u) { union { unsigned u; float f; } v; v.u = u & 0xFFFF0000u; return v.f; }

// Chebyshev basis from 2 packed bf16 features -> 8 bf16 A-fragment
__device__ inline bf16x8 cheb_frag(unsigned v) {
    float hx[2] = {bf_lo(v), bf_hi(v)};
    short t[8];
#pragma unroll
    for (int q = 0; q < 2; q++) {
        float xx = fminf(fmaxf(hx[q], -15.f), 15.f);
        float e  = __expf(2.f * xx);
        float tt = (e - 1.f) / (e + 1.f);     // tanh
        float T2 = 2.f * tt * tt - 1.f;
        float T3 = 2.f * tt * T2 - tt;
        t[q * 4 + 0] = (short)0x3F80;         // bf16(1.0)
        t[q * 4 + 1] = f2bf(tt);
        t[q * 4 + 2] = f2bf(T2);
        t[q * 4 + 3] = f2bf(T3);
    }
    return *(bf16x8*)&t[0];
}

// ---------------------------------------------------------------------------
// Merged repacks, launched BEFORE prep (prep's gemm reads Wmat -> must be
// a separate ordered launch, NOT fused; fusing raced in the r9 draft).
// ---------------------------------------------------------------------------
__global__ __launch_bounds__(256) void repack_all(const float* __restrict__ cheb,
                                                  const float* __restrict__ W,
                                                  const float* __restrict__ Wout,
                                                  unsigned short* __restrict__ Bmat,
                                                  unsigned short* __restrict__ Wmat,
                                                  unsigned short* __restrict__ C2W) {
    const int b = blockIdx.x;
    if (b < 256) {
        int idx = b * 256 + threadIdx.x;       // < 128*512
        int o = idx >> 9;
        int k = idx & 511;
        int i = k >> 2;
        int d = k & 3;
        Bmat[idx] = (unsigned short)f2bf(cheb[i * 512 + o * 4 + d]);
    } else if (b < 512) {
        int idx = (b - 256) * 256 + threadIdx.x;
        int o = idx >> 9;
        int k = idx & 511;
        Wmat[idx] = (k < IN_DIM) ? (unsigned short)f2bf(W[k * HID + o]) : 0;
    } else {
        int idx = (b - 512) * 256 + threadIdx.x;   // < 16*512
        int o16 = idx >> 9;
        int k   = idx & 511;
        const float* cb = cheb + 65536 + (k >> 2) * 512 + (k & 3);
        float s = 0.f;
#pragma unroll 4
        for (int o = 0; o < 128; o++) s += cb[o * 4] * Wout[o * 16 + o16];
        C2W[o16 * 512 + k] = (unsigned short)f2bf(s);
    }
}

// ---------------------------------------------------------------------------
// PREP super-kernel: blocks [0,NG_GEMM) run gemm_xw (h = x @ W_in, A direct
// global->reg, B LDS dbuf from the PRE-BUILT Wmat); remainder runs edge
// binning. Data-independent: gemm writes hA; bin writes bbuf(=hB, dead until
// spmm1) + bcnt. Overlaps ~90 us of serial work.
// ---------------------------------------------------------------------------
__global__ __launch_bounds__(256, 4) void prep_kernel(const float* __restrict__ x,
                                                      const int* __restrict__ ei,
                                                      const unsigned short* __restrict__ Wmat,
                                                      unsigned short* __restrict__ hA,
                                                      int* __restrict__ bcnt,
                                                      unsigned* __restrict__ bbuf) {
    __shared__ __align__(16) short Bs[2][128][40];   // 20.5 KB (gemm blocks only)
    const int tid = threadIdx.x;

    if (blockIdx.x < NG_GEMM) {
        // ---- gemm_xw: 64x128 tile, A global->reg, B LDS dbuf -------------
        const int lane = tid & 63;
        const int wave = tid >> 6;
        const int quad = lane >> 4;
        const int l16  = lane & 15;
        const int n0   = blockIdx.x * 64;
        const int br   = tid >> 1;     // B row 0..127
        const int bh   = tid & 1;      // 16-short segment

        int row = n0 + wave * 16 + l16; if (row >= N_NODES) row = N_NODES - 1;
        const float* __restrict__ xrow = x + (long)row * IN_DIM;

        f32x4 acc[8];
#pragma unroll
        for (int nt = 0; nt < 8; nt++)
#pragma unroll
            for (int r = 0; r < 4; r++) acc[nt][r] = 0.f;

        auto loadA = [&](int kt, float (&v)[8]) {
            const int kb = kt * 32 + quad * 8;
            if (kb + 8 <= IN_DIM) {
                const float4* s4 = (const float4*)(xrow + kb);
                float4 a0 = s4[0], a1 = s4[1];
                v[0]=a0.x; v[1]=a0.y; v[2]=a0.z; v[3]=a0.w;
                v[4]=a1.x; v[5]=a1.y; v[6]=a1.z; v[7]=a1.w;
            } else {
#pragma unroll
                for (int q = 0; q < 8; q++) v[q] = (kb + q < IN_DIM) ? xrow[kb + q] : 0.f;
            }
        };
        auto loadB = [&](int kt, bf16x8 (&w)[2]) {
            w[0] = *(const bf16x8*)&Wmat[br * 512 + kt * 32 + bh * 16];
            w[1] = *(const bf16x8*)&Wmat[br * 512 + kt * 32 + bh * 16 + 8];
        };
        auto storeB = [&](int buf, const bf16x8 (&w)[2]) {
            *(bf16x8*)&Bs[buf][br][bh * 16]     = w[0];
            *(bf16x8*)&Bs[buf][br][bh * 16 + 8] = w[1];
        };
        auto mfmaTile = [&](int buf, const float (&v)[8]) {
            short t[8];
#pragma unroll
            for (int q = 0; q < 8; q++) t[q] = f2bf(v[q]);
            bf16x8 a = *(bf16x8*)&t[0];
#pragma unroll
            for (int nt = 0; nt < 8; nt++) {
                bf16x8 b = *(const bf16x8*)&Bs[buf][nt * 16 + l16][quad * 8];
                acc[nt] = __builtin_amdgcn_mfma_f32_16x16x32_bf16(a, b, acc[nt], 0, 0, 0);
            }
        };

        float  va[8], vb[8];
        bf16x8 wa[2], wb[2];
        loadA(0, va); loadB(0, wa);
        for (int kt = 0; kt < 16; kt += 2) {
            storeB(0, wa);
            loadB(kt + 1, wb);
            loadA(kt + 1, vb);
            __syncthreads();
            mfmaTile(0, va);
            storeB(1, wb);
            if (kt + 2 < 16) { loadB(kt + 2, wa); loadA(kt + 2, va); }
            __syncthreads();
            mfmaTile(1, vb);
        }

        int mrow = n0 + wave * 16 + quad * 4;
#pragma unroll
        for (int r = 0; r < 4; r++) {
            int n = mrow + r;
            if (n < N_NODES) {
#pragma unroll
                for (int nt = 0; nt < 8; nt++)
                    hA[(long)n * HID + nt * 16 + l16] = (unsigned short)f2bf(acc[nt][r]);
            }
        }
    } else {
        // ---- bin: bucket each edge by row>>7 ------------------------------
        int e = (blockIdx.x - NG_GEMM) * 256 + tid;
        if (e < N_EDGES) {
            int r = ei[e];
            int c = ei[N_EDGES + e];
            int b = r >> 7;
            int p = atomicAdd(&bcnt[b * 16], 1);   // stride 64 B: spread L2 slices
            if (p < BCAP) bbuf[b * BCAP + p] = ((unsigned)(r & 127) << 17) | (unsigned)c;
        }
    }
}

// ---------------------------------------------------------------------------
// place: per-bucket local histogram + scan; bucket's global base claimed via
// ONE atomic ticket (replaces the bscan kernel). Rows get row_start+row_cnt;
// segments need not be in row order.
// ---------------------------------------------------------------------------
__global__ __launch_bounds__(256) void place_kernel(const unsigned* __restrict__ buf,
                                                    const int* __restrict__ bcnt,
                                                    int* __restrict__ gctr,
                                                    int* __restrict__ row_start,
                                                    int* __restrict__ row_cnt,
                                                    int* __restrict__ col_sorted) {
    __shared__ int hist[128];
    __shared__ int scan[128];
    __shared__ int cur[128];
    __shared__ int base_s;
    const int b = blockIdx.x, tid = threadIdx.x;
    int cnt = bcnt[b * 16]; if (cnt > BCAP) cnt = BCAP;
    if (tid < 128) hist[tid] = 0;
    __syncthreads();
    for (int i = tid; i < cnt; i += 256)
        atomicAdd(&hist[buf[b * BCAP + i] >> 17], 1);
    __syncthreads();
    if (tid < 128) scan[tid] = hist[tid];
    __syncthreads();
    for (int off = 1; off < 128; off <<= 1) {
        int t = (tid < 128 && tid >= off) ? scan[tid - off] : 0;
        __syncthreads();
        if (tid < 128) scan[tid] += t;
        __syncthreads();
    }
    if (tid == 0) base_s = atomicAdd(gctr, scan[127]);   // ticket for this bucket
    __syncthreads();
    const int base = base_s;
    if (tid < 128) {
        int excl = scan[tid] - hist[tid] + base;
        cur[tid] = excl;
        int r = b * 128 + tid;
        if (r < N_NODES) { row_start[r] = excl; row_cnt[r] = hist[tid]; }
    }
    __syncthreads();
    for (int i = tid; i < cnt; i += 256) {
        unsigned u = buf[b * BCAP + i];
        int rl = (int)(u >> 17);
        int c  = (int)(u & 0x1FFFFu);
        int pos = atomicAdd(&cur[rl], 1);
        col_sorted[pos] = c;
    }
}

// ---------------------------------------------------------------------------
// MFMA GEMM 2 (layer 0): out = Basis(h) @ C1  [N x 512]@[512 x 128]
// A via upfront register preload + per-kt basis. B dbuf'd.
// ---------------------------------------------------------------------------
__global__ __launch_bounds__(256, 4) void cheb_gemm(const unsigned short* __restrict__ h,
                                                    const unsigned short* __restrict__ Bmat,
                                                    unsigned short* __restrict__ out) {
    __shared__ __align__(16) short Bs[2][128][40];
    const int tid  = threadIdx.x;
    const int lane = tid & 63;
    const int wave = tid >> 6;
    const int quad = lane >> 4;
    const int l16  = lane & 15;
    const int n0   = blockIdx.x * 64;
    const int br   = tid >> 1;
    const int bh   = tid & 1;

    int row = n0 + wave * 16 + l16; if (row >= N_NODES) row = N_NODES - 1;
    const unsigned short* __restrict__ hrow = h + (long)row * HID;

    unsigned hreg[16];
#pragma unroll
    for (int kt = 0; kt < 16; kt++)
        hreg[kt] = *(const unsigned*)(hrow + kt * 8 + quad * 2);

    f32x4 acc[8];
#pragma unroll
    for (int nt = 0; nt < 8; nt++)
#pragma unroll
        for (int r = 0; r < 4; r++) acc[nt][r] = 0.f;

    auto loadB = [&](int kt, bf16x8 (&w)[2]) {
        w[0] = *(const bf16x8*)&Bmat[br * 512 + kt * 32 + bh * 16];
        w[1] = *(const bf16x8*)&Bmat[br * 512 + kt * 32 + bh * 16 + 8];
    };
    auto storeB = [&](int buf, const bf16x8 (&w)[2]) {
        *(bf16x8*)&Bs[buf][br][bh * 16]     = w[0];
        *(bf16x8*)&Bs[buf][br][bh * 16 + 8] = w[1];
    };
    auto mfmaTile = [&](int buf, int kt) {
        bf16x8 a = cheb_frag(hreg[kt]);
#pragma unroll
        for (int nt = 0; nt < 8; nt++) {
            bf16x8 b = *(const bf16x8*)&Bs[buf][nt * 16 + l16][quad * 8];
            acc[nt] = __builtin_amdgcn_mfma_f32_16x16x32_bf16(a, b, acc[nt], 0, 0, 0);
        }
    };

    bf16x8 wa[2], wb[2];
    loadB(0, wa);
    for (int kt = 0; kt < 16; kt += 2) {
        storeB(0, wa);
        loadB(kt + 1, wb);
        __syncthreads();
        mfmaTile(0, kt);
        storeB(1, wb);
        if (kt + 2 < 16) loadB(kt + 2, wa);
        __syncthreads();
        mfmaTile(1, kt + 1);
    }

    {
        int mrow = n0 + wave * 16 + quad * 4;
#pragma unroll
        for (int r = 0; r < 4; r++) {
            int n = mrow + r;
            if (n < N_NODES) {
#pragma unroll
                for (int nt = 0; nt < 8; nt++)
                    out[(long)n * HID + nt * 16 + l16] = (unsigned short)f2bf(acc[nt][r]);
            }
        }
    }
}

// ---------------------------------------------------------------------------
// MFMA GEMM 3 (layer 1 + W_out folded): z = Basis(h) @ C2W  [N x 512]@[512 x 16]
// B LDS-resident; A in registers; one barrier total.
// ---------------------------------------------------------------------------
__global__ __launch_bounds__(256, 4) void cheb16_gemm(const unsigned short* __restrict__ h,
                                                      const unsigned short* __restrict__ C2W,
                                                      float* __restrict__ z) {
    __shared__ __align__(16) short Bs16[16][520];
    const int tid  = threadIdx.x;
    const int lane = tid & 63;
    const int wave = tid >> 6;
    const int quad = lane >> 4;
    const int l16  = lane & 15;
    const int n0   = blockIdx.x * 64;

    {
        int o16 = tid >> 4;
        int seg = tid & 15;
        *(bf16x8*)&Bs16[o16][seg * 32]      = *(const bf16x8*)&C2W[o16 * 512 + seg * 32];
        *(bf16x8*)&Bs16[o16][seg * 32 + 8]  = *(const bf16x8*)&C2W[o16 * 512 + seg * 32 + 8];
        *(bf16x8*)&Bs16[o16][seg * 32 + 16] = *(const bf16x8*)&C2W[o16 * 512 + seg * 32 + 16];
        *(bf16x8*)&Bs16[o16][seg * 32 + 24] = *(const bf16x8*)&C2W[o16 * 512 + seg * 32 + 24];
    }

    int row = n0 + wave * 16 + l16; if (row >= N_NODES) row = N_NODES - 1;
    const unsigned short* __restrict__ hrow = h + (long)row * HID;

    unsigned hreg[16];
#pragma unroll
    for (int kt = 0; kt < 16; kt++)
        hreg[kt] = *(const unsigned*)(hrow + kt * 8 + quad * 2);

    f32x4 acc;
#pragma unroll
    for (int r = 0; r < 4; r++) acc[r] = 0.f;

    __syncthreads();   // B ready; the only barrier

#pragma unroll
    for (int kt = 0; kt < 16; kt++) {
        bf16x8 a = cheb_frag(hreg[kt]);
        bf16x8 b = *(const bf16x8*)&Bs16[l16][kt * 32 + quad * 8];
        acc = __builtin_amdgcn_mfma_f32_16x16x32_bf16(a, b, acc, 0, 0, 0);
    }

    {
        int mrow = n0 + wave * 16 + quad * 4;
#pragma unroll
        for (int r = 0; r < 4; r++) {
            int n = mrow + r;
            if (n < N_NODES) z[n * 16 + l16] = acc[r];
        }
    }
}

// ---------------------------------------------------------------------------
// SpMM gather (128-wide bf16, ROW-major h): wave/row; 16 lanes x uint4 per
// edge, 4 edges/instr, unrolled x2. Row bounds via row_start + row_cnt.
// ---------------------------------------------------------------------------
__global__ __launch_bounds__(256) void spmm_gather(const int* __restrict__ row_start,
                                                   const int* __restrict__ row_cnt,
                                                   const int* __restrict__ col_sorted,
                                                   const unsigned short* __restrict__ h,
                                                   unsigned short* __restrict__ out) {
    const int wid  = (blockIdx.x * 256 + threadIdx.x) >> 6;   // row
    const int lane = threadIdx.x & 63;
    const int sub  = lane >> 4;        // edge slot 0..3
    const int fl   = lane & 15;        // 16-byte feature slice 0..15
    if (wid >= N_NODES) return;
    const int s = row_start[wid];
    const int e = s + row_cnt[wid];
    const uint4* __restrict__ h4 = (const uint4*)h;   // one row = 16 uint4

    float a[8], b[8];
#pragma unroll
    for (int q = 0; q < 8; q++) { a[q] = 0.f; b[q] = 0.f; }

    int j = s;
    for (; j + 8 <= e; j += 8) {
        int c0 = col_sorted[j + sub];
        int c1 = col_sorted[j + 4 + sub];
        uint4 u0 = h4[c0 * 16 + fl];
        uint4 u1 = h4[c1 * 16 + fl];
        a[0] += bf_lo(u0.x); a[1] += bf_hi(u0.x);
        a[2] += bf_lo(u0.y); a[3] += bf_hi(u0.y);
        a[4] += bf_lo(u0.z); a[5] += bf_hi(u0.z);
        a[6] += bf_lo(u0.w); a[7] += bf_hi(u0.w);
        b[0] += bf_lo(u1.x); b[1] += bf_hi(u1.x);
        b[2] += bf_lo(u1.y); b[3] += bf_hi(u1.y);
        b[4] += bf_lo(u1.z); b[5] += bf_hi(u1.z);
        b[6] += bf_lo(u1.w); b[7] += bf_hi(u1.w);
    }
    for (; j < e; j += 4) {
        int idx = j + sub;
        float m = (idx < e) ? 1.f : 0.f;
        int ci = (idx < e) ? idx : (e - 1);
        int c = col_sorted[ci];
        uint4 u = h4[c * 16 + fl];
        a[0] = fmaf(m, bf_lo(u.x), a[0]); a[1] = fmaf(m, bf_hi(u.x), a[1]);
        a[2] = fmaf(m, bf_lo(u.y), a[2]); a[3] = fmaf(m, bf_hi(u.y), a[3]);
        a[4] = fmaf(m, bf_lo(u.z), a[4]); a[5] = fmaf(m, bf_hi(u.z), a[5]);
        a[6] = fmaf(m, bf_lo(u.w), a[6]); a[7] = fmaf(m, bf_hi(u.w), a[7]);
    }
#pragma unroll
    for (int q = 0; q < 8; q++) a[q] += b[q];
#pragma unroll
    for (int q = 0; q < 8; q++) {
        a[q] += __shfl_xor(a[q], 16);
        a[q] += __shfl_xor(a[q], 32);
    }
    if (sub == 0) {
        unsigned w0 = (unsigned)(unsigned short)f2bf(a[0]) | ((unsigned)(unsigned short)f2bf(a[1]) << 16);
        unsigned w1 = (unsigned)(unsigned short)f2bf(a[2]) | ((unsigned)(unsigned short)f2bf(a[3]) << 16);
        unsigned w2 = (unsigned)(unsigned short)f2bf(a[4]) | ((unsigned)(unsigned short)f2bf(a[5]) << 16);
        unsigned w3 = (unsigned)(unsigned short)f2bf(a[6]) | ((unsigned)(unsigned short)f2bf(a[7]) << 16);
        uint4 pw; pw.x = w0; pw.y = w1; pw.z = w2; pw.w = w3;
        ((uint4*)out)[wid * 16 + fl] = pw;
    }
}

// ---------------------------------------------------------------------------
// Final spmm (16-wide f32) + log_softmax fused; bounds via row_start+row_cnt.
// ---------------------------------------------------------------------------
__global__ __launch_bounds__(256) void spmm_out(const int* __restrict__ row_start,
                                                const int* __restrict__ row_cnt,
                                                const int* __restrict__ col_sorted,
                                                const float* __restrict__ z,
                                                float* __restrict__ out) {
    const int wid  = (blockIdx.x * 256 + threadIdx.x) >> 6;
    const int lane = threadIdx.x & 63;
    const int sub  = lane >> 4;
    const int fl   = lane & 15;
    if (wid >= N_NODES) return;
    const int s = row_start[wid];
    const int e = s + row_cnt[wid];

    float a0 = 0.f, a1 = 0.f;
    int j = s;
    for (; j + 8 <= e; j += 8) {
        int c0 = col_sorted[j + sub];
        int c1 = col_sorted[j + 4 + sub];
        a0 += z[c0 * 16 + fl];
        a1 += z[c1 * 16 + fl];
    }
    for (; j < e; j += 4) {
        int idx = j + sub;
        float m = (idx < e) ? 1.f : 0.f;
        int ci = (idx < e) ? idx : (e - 1);
        a0 = fmaf(m, z[col_sorted[ci] * 16 + fl], a0);
    }
    float v = a0 + a1;
    v += __shfl_xor(v, 16);
    v += __shfl_xor(v, 32);
    float mx = v;
#pragma unroll
    for (int m = 8; m >= 1; m >>= 1) mx = fmaxf(mx, __shfl_xor(mx, m));
    float ex = expf(v - mx);
    float se = ex;
#pragma unroll
    for (int m = 8; m >= 1; m >>= 1) se += __shfl_xor(se, m);
    if (sub == 0) out[wid * 16 + fl] = v - mx - logf(se);
}

// ---------------------------------------------------------------------------

extern "C" void kernel_launch(void* const* d_in, const int* in_sizes, int n_in,
                              void* d_out, int out_size, void* d_ws, size_t ws_size,
                              hipStream_t stream) {
    const float* x     = (const float*)d_in[0];
    const int*   ei    = (const int*)d_in[1];
    const float* W_in  = (const float*)d_in[2];
    const float* cheb  = (const float*)d_in[3];
    const float* W_out = (const float*)d_in[4];
    float* out = (float*)d_out;

    char* p = (char*)d_ws;
    unsigned short* hA   = (unsigned short*)p; p += (size_t)N_NODES * HID * 2;   // 25.6 MB
    unsigned short* hB   = (unsigned short*)p; p += (size_t)N_NODES * HID * 2;   // 25.6 MB
    int*   col_sorted    = (int*)p;            p += (size_t)N_EDGES * 4;         // 6.4 MB
    unsigned short* Bmat = (unsigned short*)p; p += (size_t)HID * KDIM * 2;      // 128 KB (layer-0)
    unsigned short* Wmat = (unsigned short*)p; p += (size_t)HID * KDIM * 2;      // 128 KB
    unsigned short* C2W  = (unsigned short*)p; p += (size_t)16 * KDIM * 2;       // 16 KB
    float* zbuf          = (float*)p;          p += (size_t)N_NODES * 16 * 4;    // 6.4 MB
    int*   row_start     = (int*)p;            p += (size_t)N_NODES * 4;         // 400 KB
    int*   row_cnt       = (int*)p;            p += (size_t)N_NODES * 4;         // 400 KB
    int*   bcnt          = (int*)p;            p += (size_t)(NB * 16 + 16) * 4;  // 50 KB + gctr slot

    int* gctr = bcnt + NB * 16;   // zeroed by the same memset

    // bucket buffer aliases hB (dead until spmm1 writes it; prep's gemm
    // section writes hA only, so bin ∥ gemm is safe)
    unsigned* bbuf = (unsigned*)hB;

    const int nblk_prep = NG_GEMM + NG_BIN;            // 7813
    const int nblk_gemm = (N_NODES + 63) / 64;         // 1563
    const int nblk_spmm = (N_NODES + 3) / 4;           // 25000

    hipMemsetAsync(bcnt, 0, (size_t)(NB * 16 + 16) * 4, stream);

    repack_all<<<544, 256, 0, stream>>>(cheb, W_in, W_out, Bmat, Wmat, C2W);

    // gemm_xw ∥ bin in one launch (both read-only on inputs; disjoint outputs)
    prep_kernel<<<nblk_prep, 256, 0, stream>>>(x, ei, Wmat, hA, bcnt, bbuf);
    place_kernel<<<NB, 256, 0, stream>>>(bbuf, bcnt, gctr, row_start, row_cnt, col_sorted);

    spmm_gather<<<nblk_spmm, 256, 0, stream>>>(row_start, row_cnt, col_sorted, hA, hB);

    cheb_gemm<<<nblk_gemm, 256, 0, stream>>>(hB, Bmat, hA);                    // layer 0
    spmm_gather<<<nblk_spmm, 256, 0, stream>>>(row_start, row_cnt, col_sorted, hA, hB);

    cheb16_gemm<<<nblk_gemm, 256, 0, stream>>>(hB, C2W, zbuf);                 // layer 1 + W_out
    spmm_out<<<nblk_spmm, 256, 0, stream>>>(row_start, row_cnt, col_sorted, zbuf, out); // spmm + lsm
}